// Round 9
// baseline (180.368 us; speedup 1.0000x reference)
//
#include <hip/hip_runtime.h>
#include <math.h>

// Problem constants (from reference setup_inputs)
#define BB 8
#define CC 192
#define HH 128
#define WW 128
#define NUNIT (BB * CC * (HH / 2))   // 98304 row-pair units (wave = 2 rows)
#define NBLK  2048
#define NWAVES (NBLK * 4)            // 8192 waves = 32 per CU (R5's saturation recipe)
#define NIT   (NUNIT / NWAVES)       // 12 grid-stride iterations (exact)

// R5 A/B: identical grid / sweep order / occupancy to the TA-saturated R5
// (95.6 cyc/inst), but 3 vmem insts per 64 outputs instead of 4: the up-row
// and down-row loads are replaced by ONE "outer" load (lo half: row r-1,
// hi half: row r+2) plus a half-swap shuffle of the center row -- each half
// of the wave serves as the other's middle neighbor.

typedef float vf4 __attribute__((ext_vector_type(4)));

__device__ __forceinline__ float col9(float a0, float a1, float a2,
                                      float b0, float b1, float b2,
                                      float c0, float c1, float c2,
                                      float th, const float* kk) {
    float m;
    m = fmaf(th, kk[0], a0);
    m = fmaxf(m, fmaf(th, kk[1], a1));
    m = fmaxf(m, fmaf(th, kk[2], a2));
    m = fmaxf(m, fmaf(th, kk[3], b0));
    m = fmaxf(m, fmaf(th, kk[4], b1));
    m = fmaxf(m, fmaf(th, kk[5], b2));
    m = fmaxf(m, fmaf(th, kk[6], c0));
    m = fmaxf(m, fmaf(th, kk[7], c1));
    m = fmaxf(m, fmaf(th, kk[8], c2));
    return m;
}

__global__ __launch_bounds__(256) void dynmorph_kernel(
    const float* __restrict__ x,      // [B, C, H, W]
    const float* __restrict__ kern,   // [C, 9]
    const float* __restrict__ gw,     // [C]
    const float* __restrict__ gb,     // [C]
    float* __restrict__ out)          // [B, C, H, W]
{
    const int tid  = threadIdx.x;
    const int lane = tid & 63;
    const int wg   = lane & 31;       // column group within a row
    const int hf   = lane >> 5;       // wave half: row r (0) / row r+1 (1)
    const int col  = wg * 4;
    const int wid  = __builtin_amdgcn_readfirstlane(blockIdx.x * 4 + (tid >> 6));

#pragma unroll
    for (int k = 0; k < NIT; ++k) {
        const int u  = k * NWAVES + wid;    // unit id (wave-uniform, copy-ordered sweep)
        const int bc = u >> 6;              // image id = b*C + c
        const int r  = (u & 63) * 2;        // first row of the pair (0..126, even)
        const int c  = bc % CC;

        const float* xb = x   + (size_t)bc * (HH * WW);
        float*       ob = out + (size_t)bc * (HH * WW);

        float kk[9];
#pragma unroll
        for (int q = 0; q < 9; ++q) kk[q] = kern[c * 9 + q];
        const float gwc = gw[c];
        const float gbc = gb[c];

        // ---- 2 loads ----
        const int rc = r + hf;                          // own center row
        const vf4 Bv = *(const vf4*)(xb + rc * WW + col);

        const int ro  = hf ? (r + 2) : (r - 1);         // outer row
        const int roc = ro < 0 ? 0 : (ro > HH - 1 ? HH - 1 : ro);
        vf4 Ov = *(const vf4*)(xb + roc * WW + col);
        const int oval = hf ? (ro < HH) : (ro >= 0);
        if (!oval) Ov = (vf4)(0.0f);                    // image top/bottom zero halo

        // ---- Column halos (within 32-lane row groups; wg masks also fix
        //      the lane31<->lane32 cross-half leakage = W-edge zero halo) ----
        float bl = __shfl_up(Bv.w, 1), br = __shfl_down(Bv.x, 1);
        bl = (wg == 0) ? 0.0f : bl;  br = (wg == 31) ? 0.0f : br;
        float ol = __shfl_up(Ov.w, 1), orr = __shfl_down(Ov.x, 1);
        ol = (wg == 0) ? 0.0f : ol;  orr = (wg == 31) ? 0.0f : orr;

        // ---- Half-swap: other half's center row + its halos ----
        const int sl = lane ^ 32;
        vf4 Sv;
        Sv.x = __shfl(Bv.x, sl); Sv.y = __shfl(Bv.y, sl);
        Sv.z = __shfl(Bv.z, sl); Sv.w = __shfl(Bv.w, sl);
        const float slh = __shfl(bl, sl);
        const float srh = __shfl(br, sl);

        // ---- Assemble 3x(row) neighborhood for own output row rc ----
        // hf=0 (row r):   A = Ov (r-1),  C = Sv (r+1 = hi center)
        // hf=1 (row r+1): A = Sv (r),    C = Ov (r+2)
        const vf4   A  = hf ? Sv  : Ov;
        const vf4   Cv = hf ? Ov  : Sv;
        const float aL = hf ? slh : ol,  aR = hf ? srh : orr;
        const float cL = hf ? ol  : slh, cR = hf ? orr : srh;

        const float t0 = __builtin_amdgcn_rcpf(1.0f + __expf(-fmaf(Bv.x, gwc, gbc)));
        const float t1 = __builtin_amdgcn_rcpf(1.0f + __expf(-fmaf(Bv.y, gwc, gbc)));
        const float t2 = __builtin_amdgcn_rcpf(1.0f + __expf(-fmaf(Bv.z, gwc, gbc)));
        const float t3 = __builtin_amdgcn_rcpf(1.0f + __expf(-fmaf(Bv.w, gwc, gbc)));

        vf4 o;
        o.x = col9(aL,   A.x,  A.y,
                   bl,   Bv.x, Bv.y,
                   cL,   Cv.x, Cv.y, t0, kk);
        o.y = col9(A.x,  A.y,  A.z,
                   Bv.x, Bv.y, Bv.z,
                   Cv.x, Cv.y, Cv.z, t1, kk);
        o.z = col9(A.y,  A.z,  A.w,
                   Bv.y, Bv.z, Bv.w,
                   Cv.y, Cv.z, Cv.w, t2, kk);
        o.w = col9(A.z,  A.w,  aR,
                   Bv.z, Bv.w, br,
                   Cv.z, Cv.w, cR, t3, kk);

        // ---- 1 store (1KB contiguous across the wave) ----
        *(vf4*)(ob + rc * WW + col) = o;
    }
}

extern "C" void kernel_launch(void* const* d_in, const int* in_sizes, int n_in,
                              void* d_out, int out_size, void* d_ws, size_t ws_size,
                              hipStream_t stream) {
    const float* x    = (const float*)d_in[0];
    const float* kern = (const float*)d_in[1];
    const float* gw   = (const float*)d_in[2];
    const float* gb   = (const float*)d_in[3];
    float* out        = (float*)d_out;

    dim3 grid(NBLK);    // 2048 blocks = 8/CU resident, 32 waves/CU (R5 recipe)
    dim3 block(256);
    dynmorph_kernel<<<grid, block, 0, stream>>>(x, kern, gw, gb, out);
}